// Round 7
// baseline (171.042 us; speedup 1.0000x reference)
//
#include <hip/hip_runtime.h>
#include <stdint.h>

// Problem constants (fixed by the reference)
#define BATCH   4096
#define IN_DIM  1024
#define OUT_DIM 1024

typedef __bf16 bf16x8 __attribute__((ext_vector_type(8)));
typedef float  f32x4  __attribute__((ext_vector_type(4)));

// fp32 -> bf16 bits, round-to-nearest-even
__device__ __forceinline__ uint16_t f2bf(float f) {
    union { float f; uint32_t u; } v; v.f = f;
    uint32_t u = v.u;
    uint32_t r = (u + 0x7FFFu + ((u >> 16) & 1u)) >> 16;
    return (uint16_t)r;
}

__device__ __forceinline__ float bf2f(uint16_t h) {
    union { uint32_t u; float f; } v; v.u = ((uint32_t)h) << 16;
    return v.f;
}

// ---------------------------------------------------------------------------
// prep: blocks 0..4095   -> convert x row b to bf16, compute alpha[b][0..3]
//       blocks 4096..8191 -> convert W (flat 4M floats) to bf16
// ---------------------------------------------------------------------------
__global__ __launch_bounds__(256) void prep(
    const float* __restrict__ x, const float* __restrict__ phase,
    const float* __restrict__ basis, const float* __restrict__ W,
    uint16_t* __restrict__ xb, uint16_t* __restrict__ Wb,
    float* __restrict__ alphaWS)
{
    const int bid = blockIdx.x;
    const int tid = threadIdx.x;

    if (bid < BATCH) {
        const int b = bid;
        const float HALF_PI = 1.5707963267948966f;
        float s  = phase[b] / HALF_PI;
        int   q  = (int)floorf(s);
        q = q < 0 ? 0 : (q > 3 ? 3 : q);
        float t  = s - (float)q;
        float t2 = t * t, t3 = t2 * t;

        float coef[4];
#pragma unroll
        for (int j = 0; j < 4; ++j)
            coef[j] = t3 * basis[j] + t2 * basis[4 + j] + t * basis[8 + j] + basis[12 + j];

        // CPI[q][k] = (q+k+3)%4  =>  alpha[c] = coef[(c - q + 1) & 3]
        if (tid < 4) alphaWS[b * 4 + tid] = coef[(tid - q + 1) & 3];

        float4 xv = ((const float4*)(x + (size_t)b * IN_DIM))[tid];
        ushort4 o;
        o.x = f2bf(xv.x); o.y = f2bf(xv.y); o.z = f2bf(xv.z); o.w = f2bf(xv.w);
        ((ushort4*)(xb + (size_t)b * IN_DIM))[tid] = o;
    } else {
        const int j = bid - BATCH;                 // 0..4095, W has 1M float4s
        float4 wv = ((const float4*)W)[j * 256 + tid];
        ushort4 o;
        o.x = f2bf(wv.x); o.y = f2bf(wv.y); o.z = f2bf(wv.z); o.w = f2bf(wv.w);
        ((ushort4*)Wb)[j * 256 + tid] = o;
    }
}

// ---------------------------------------------------------------------------
// gemm_fused: one block = one 128x64 out-tile, 8 waves (512 thr).
// Wave wid -> (m-half mh = wid>>2, control point c = wid&3): computes the
// 64x64 sub-tile (mh, c) via the round-0-verified 4x4 MFMA fragment loop.
// Staging per K-step: A 128x64 SHARED by all 8 waves (2 slices/wave),
// B [4][64x64] shared pairwise (4 slices/wave) -> 6 global_load_lds/wave
// per K-step, 48 KB per 256 MFMA (was 10 loads / 80 KB in the round-6
// 64x64x4c shape). XOR swizzle on global source; read chunk =
// (ks*4+quad)^(lane&7); all row exprs keep the (lane&15) form so
// row&7 == lane&7 still holds.
// Epilogue: in-block c-reduction (NO cross-block sync — rounds 2-5 refuted
// atomics / UC loads / fences / cooperative launch). Two phases, one per
// m-half: waves of that half publish alpha-scaled bf16 partials to Ps
// (LDS alias, stride-66 pad), then all 512 threads combine + add
// alpha-weighted bias, write fp32 out.
// grid (32,16) = 512 blocks = 2/CU; LDS 48 KB; VGPR capped at 128.
// ---------------------------------------------------------------------------
#define PS 66   // padded row stride (elems) for epilogue exchange

__global__ __launch_bounds__(512, 4) void gemm_fused(
    const uint16_t* __restrict__ xb, const uint16_t* __restrict__ Wb,
    const float* __restrict__ alphaWS, const float* __restrict__ biases,
    float* __restrict__ out)
{
    __shared__ uint16_t lds[128 * 64 + 4 * 64 * 64];  // As 16KB | Bs 32KB
    uint16_t* As = lds;                                // [128][64]
    uint16_t* Bs = lds + 8192;                         // [4][64][64]
    uint16_t* Ps = lds;                                // epilogue alias [4][64][PS] (33.8KB)

    const int tid  = threadIdx.x;
    const int lane = tid & 63;
    const int wid  = tid >> 6;        // 0..7
    const int cw   = wid & 3;         // control point of this wave
    const int mh   = wid >> 2;        // m-half of this wave
    const int tileM = blockIdx.x * 128;
    const int tileN = blockIdx.y * 64;

    f32x4 acc[4][4];
#pragma unroll
    for (int mi = 0; mi < 4; ++mi)
#pragma unroll
        for (int ni = 0; ni < 4; ++ni)
            acc[mi][ni] = (f32x4){0.f, 0.f, 0.f, 0.f};

    // staging: slice = 8 rows x 64 cols; lane l -> row l>>3, phys chunk l&7,
    // source global chunk = (l&7) ^ (l>>3)   (XOR swizzle, round-0 verified)
    const int srow = lane >> 3;
    const int gchunk = ((lane & 7) ^ srow) * 8;

    const uint16_t* Ag = xb + (size_t)tileM * 1024;

    const int quad = lane >> 4;
    const int l7   = lane & 7;

    for (int kt = 0; kt < 16; ++kt) {
        const int k0 = kt * 64;
        // A: 16 slices (128 rows), wave stages 2 — shared by all 8 waves
#pragma unroll
        for (int j = 0; j < 2; ++j) {
            const int s = wid * 2 + j;
            const uint16_t* ga = Ag + (size_t)(s * 8 + srow) * 1024 + k0 + gchunk;
            __builtin_amdgcn_global_load_lds(
                (const __attribute__((address_space(1))) void*)ga,
                (__attribute__((address_space(3))) void*)(As + s * 512), 16, 0, 0);
        }
        // B: 32 slices (4 c x 8), wave stages 4
#pragma unroll
        for (int j = 0; j < 4; ++j) {
            const int g  = wid * 4 + j;           // 0..31
            const int cb = g >> 3;                // which control point
            const int sr = g & 7;                 // slice within that panel
            const uint16_t* gb = Wb + ((size_t)cb << 20)
                               + (size_t)(tileN + sr * 8 + srow) * 1024 + k0 + gchunk;
            __builtin_amdgcn_global_load_lds(
                (const __attribute__((address_space(1))) void*)gb,
                (__attribute__((address_space(3))) void*)(Bs + cb * 4096 + sr * 512), 16, 0, 0);
        }
        __syncthreads();

#pragma unroll
        for (int ks = 0; ks < 2; ++ks) {
            const int ch = (ks * 4 + quad) ^ l7;       // physical chunk
            bf16x8 af[4], bfr[4];
#pragma unroll
            for (int mi = 0; mi < 4; ++mi) {
                const int row = mh * 64 + mi * 16 + (lane & 15);
                af[mi] = *(const bf16x8*)(As + row * 64 + ch * 8);
            }
#pragma unroll
            for (int ni = 0; ni < 4; ++ni) {
                const int row = ni * 16 + (lane & 15);
                bfr[ni] = *(const bf16x8*)(Bs + cw * 4096 + row * 64 + ch * 8);
            }
#pragma unroll
            for (int mi = 0; mi < 4; ++mi)
#pragma unroll
                for (int ni = 0; ni < 4; ++ni)
                    acc[mi][ni] = __builtin_amdgcn_mfma_f32_16x16x32_bf16(
                        af[mi], bfr[ni], acc[mi][ni], 0, 0, 0);
        }
        __syncthreads();
    }

    // ---- epilogue: in-block c-reduction, one phase per m-half ----
    // C/D layout: col = lane&15, row(64-sub-tile) = mi*16 + quad*4 + r.
    // alpha for this wave's 16 output rows
    float av[4][4];
#pragma unroll
    for (int mi = 0; mi < 4; ++mi)
#pragma unroll
        for (int r = 0; r < 4; ++r)
            av[mi][r] = alphaWS[(size_t)(tileM + mh * 64 + mi * 16 + quad * 4 + r) * 4 + cw];

    const int rr   = tid >> 3;           // 0..63 combine row
    const int colb = (tid & 7) * 8;      // 8-col group

#pragma unroll
    for (int p = 0; p < 2; ++p) {
        __syncthreads();                 // guard Ps reuse across phases
        if (mh == p) {
#pragma unroll
            for (int mi = 0; mi < 4; ++mi) {
#pragma unroll
                for (int r = 0; r < 4; ++r) {
                    const int row = mi * 16 + quad * 4 + r;
#pragma unroll
                    for (int ni = 0; ni < 4; ++ni)
                        Ps[cw * (64 * PS) + row * PS + ni * 16 + (lane & 15)] =
                            f2bf(av[mi][r] * acc[mi][ni][r]);
                }
            }
        }
        __syncthreads();

        const int m = tileM + p * 64 + rr;
        const float4 al = *(const float4*)(alphaWS + (size_t)m * 4);
        const float a[4] = {al.x, al.y, al.z, al.w};

        float res[8];
#pragma unroll
        for (int j = 0; j < 8; ++j) res[j] = 0.f;

#pragma unroll
        for (int cc = 0; cc < 4; ++cc) {
            // alpha-weighted bias (16KB total, L2-hot)
            float4 b0 = *(const float4*)(biases + (size_t)cc * OUT_DIM + tileN + colb);
            float4 b1 = *(const float4*)(biases + (size_t)cc * OUT_DIM + tileN + colb + 4);
            res[0] += a[cc] * b0.x; res[1] += a[cc] * b0.y;
            res[2] += a[cc] * b0.z; res[3] += a[cc] * b0.w;
            res[4] += a[cc] * b1.x; res[5] += a[cc] * b1.y;
            res[6] += a[cc] * b1.z; res[7] += a[cc] * b1.w;
            // scaled partial (4B-aligned ushort2 reads)
            const uint16_t* pp = Ps + cc * (64 * PS) + rr * PS + colb;
#pragma unroll
            for (int jj = 0; jj < 4; ++jj) {
                uint32_t pv = *(const uint32_t*)(pp + jj * 2);
                res[jj * 2 + 0] += bf2f((uint16_t)(pv & 0xFFFFu));
                res[jj * 2 + 1] += bf2f((uint16_t)(pv >> 16));
            }
        }

        float* orow = out + (size_t)m * OUT_DIM + tileN + colb;
        float4 o0 = {res[0], res[1], res[2], res[3]};
        float4 o1 = {res[4], res[5], res[6], res[7]};
        *(float4*)(orow)     = o0;
        *(float4*)(orow + 4) = o1;
    }
}

extern "C" void kernel_launch(void* const* d_in, const int* in_sizes, int n_in,
                              void* d_out, int out_size, void* d_ws, size_t ws_size,
                              hipStream_t stream)
{
    const float* x       = (const float*)d_in[0];  // (B, IN)
    const float* phase   = (const float*)d_in[1];  // (B,)
    const float* weights = (const float*)d_in[2];  // (4, OUT, IN)
    const float* biases  = (const float*)d_in[3];  // (4, OUT)
    const float* basis   = (const float*)d_in[4];  // (4, 4)
    float* out = (float*)d_out;                    // (B, OUT)

    // Workspace: xb bf16 8 MB | Wb bf16 8 MB | alpha 64 KB
    uint16_t* xb = (uint16_t*)d_ws;
    uint16_t* Wb = xb + (size_t)BATCH * IN_DIM;
    float* alphaWS = (float*)(Wb + (size_t)4 * OUT_DIM * IN_DIM);

    prep<<<2 * BATCH, 256, 0, stream>>>(x, phase, basis, weights, xb, Wb, alphaWS);

    dim3 grid(BATCH / 128, OUT_DIM / 64);  // 512 blocks, M-fastest for L2
    gemm_fused<<<grid, 512, 0, stream>>>(xb, Wb, alphaWS, biases, out);
}

// Round 8
// 128.517 us; speedup vs baseline: 1.3309x; 1.3309x over previous
//
#include <hip/hip_runtime.h>
#include <stdint.h>

// Problem constants (fixed by the reference)
#define BATCH   4096
#define IN_DIM  1024
#define OUT_DIM 1024

typedef __bf16 bf16x8 __attribute__((ext_vector_type(8)));
typedef float  f32x4  __attribute__((ext_vector_type(4)));

// fp32 -> bf16 bits, round-to-nearest-even
__device__ __forceinline__ uint16_t f2bf(float f) {
    union { float f; uint32_t u; } v; v.f = f;
    uint32_t u = v.u;
    uint32_t r = (u + 0x7FFFu + ((u >> 16) & 1u)) >> 16;
    return (uint16_t)r;
}

__device__ __forceinline__ float bf2f(uint16_t h) {
    union { uint32_t u; float f; } v; v.u = ((uint32_t)h) << 16;
    return v.f;
}

// ---------------------------------------------------------------------------
// prep: blocks 0..4095   -> convert x row b to bf16, compute alpha[b][0..3]
//       blocks 4096..8191 -> convert W (flat 4M floats) to bf16
// ---------------------------------------------------------------------------
__global__ __launch_bounds__(256) void prep(
    const float* __restrict__ x, const float* __restrict__ phase,
    const float* __restrict__ basis, const float* __restrict__ W,
    uint16_t* __restrict__ xb, uint16_t* __restrict__ Wb,
    float* __restrict__ alphaWS)
{
    const int bid = blockIdx.x;
    const int tid = threadIdx.x;

    if (bid < BATCH) {
        const int b = bid;
        const float HALF_PI = 1.5707963267948966f;
        float s  = phase[b] / HALF_PI;
        int   q  = (int)floorf(s);
        q = q < 0 ? 0 : (q > 3 ? 3 : q);
        float t  = s - (float)q;
        float t2 = t * t, t3 = t2 * t;

        float coef[4];
#pragma unroll
        for (int j = 0; j < 4; ++j)
            coef[j] = t3 * basis[j] + t2 * basis[4 + j] + t * basis[8 + j] + basis[12 + j];

        // CPI[q][k] = (q+k+3)%4  =>  alpha[c] = coef[(c - q + 1) & 3]
        if (tid < 4) alphaWS[b * 4 + tid] = coef[(tid - q + 1) & 3];

        float4 xv = ((const float4*)(x + (size_t)b * IN_DIM))[tid];
        ushort4 o;
        o.x = f2bf(xv.x); o.y = f2bf(xv.y); o.z = f2bf(xv.z); o.w = f2bf(xv.w);
        ((ushort4*)(xb + (size_t)b * IN_DIM))[tid] = o;
    } else {
        const int j = bid - BATCH;                 // 0..4095, W has 1M float4s
        float4 wv = ((const float4*)W)[j * 256 + tid];
        ushort4 o;
        o.x = f2bf(wv.x); o.y = f2bf(wv.y); o.z = f2bf(wv.z); o.w = f2bf(wv.w);
        ((ushort4*)Wb)[j * 256 + tid] = o;
    }
}

// ---------------------------------------------------------------------------
// gemm_fused: ROUND-6 structure (best: 129.995 us total) + T3-minimum
// 2-phase software pipeline.
// One block = one 64x64 out-tile; wave wid computes control point c = wid
// over the SAME tile (A shared 64x64, B_c private 64x64). In-block
// c-reduction epilogue via LDS exchange (NO cross-block sync — atomics /
// UC loads / fences / cooperative launch all refuted in rounds 2-5).
//
// Pipeline change vs round 6 (latency-bound: loads issued AFTER the
// compute barrier exposed L2/HBM latency every K-step -> MfmaUtil 29%):
//   prologue: STAGE(buf0, kt=0)
//   loop kt:  __syncthreads()            // drains STAGE(cur), prev reads
//             if (kt<15) STAGE(cur^1, kt+1)   // issue-early: latency hides
//             COMPUTE(cur)                    //   under these 32 MFMA
//             cur ^= 1
// One barrier per K-step instead of two; the drain at loop top is cheap
// because the loads had a full MFMA phase to land. Buffers disjoint ->
// no WAR (STAGE writes cur^1, compute reads cur; cur^1's last readers
// finished before the previous barrier).
// LDS: 2 x (As 8KB + Bs 32KB) = 80KB -> 2 blocks/CU.
// Main-loop fragment math byte-identical to round 0/6 (XOR swizzle on
// global source; read chunk = (ks*4+quad)^(lane&7)).
// ---------------------------------------------------------------------------
#define PS    66      // padded row stride (elems) for epilogue exchange
#define BUFSZ 20480   // elems per double-buffer half (As 4096 + Bs 16384)

__global__ __launch_bounds__(256, 2) void gemm_fused(
    const uint16_t* __restrict__ xb, const uint16_t* __restrict__ Wb,
    const float* __restrict__ alphaWS, const float* __restrict__ biases,
    float* __restrict__ out)
{
    __shared__ uint16_t lds[2 * BUFSZ];               // 80 KB
    uint16_t* Ps = lds;                               // epilogue alias [4][64][PS] (33.8KB)

    const int tid  = threadIdx.x;
    const int lane = tid & 63;
    const int wid  = tid >> 6;        // = c for this wave
    const int tileM = blockIdx.x * 64;
    const int tileN = blockIdx.y * 64;

    f32x4 acc[4][4];
#pragma unroll
    for (int mi = 0; mi < 4; ++mi)
#pragma unroll
        for (int ni = 0; ni < 4; ++ni)
            acc[mi][ni] = (f32x4){0.f, 0.f, 0.f, 0.f};

    // staging: slice = 8 rows x 64 cols; lane l -> row l>>3, phys chunk l&7,
    // source global chunk = (l&7) ^ (l>>3)   (XOR swizzle, round-0 verified)
    const int srow = lane >> 3;
    const int gchunk = ((lane & 7) ^ srow) * 8;

    const uint16_t* Ag = xb + (size_t)tileM * 1024;
    const uint16_t* Bg = Wb + ((size_t)wid << 20) + (size_t)tileN * 1024;

    const int quad = lane >> 4;
    const int l7   = lane & 7;

    // issue this wave's 10 global_load_lds for K-step kt into buffer buf
    auto STAGE = [&](int buf, int kt) {
        const int k0 = kt * 64;
        uint16_t* As = lds + buf * BUFSZ;
        uint16_t* Bs = As + 4096;
        // A: 8 slices total, wave stages 2 (shared by all 4 waves)
#pragma unroll
        for (int j = 0; j < 2; ++j) {
            const int s = wid * 2 + j;
            const uint16_t* ga = Ag + (size_t)(s * 8 + srow) * 1024 + k0 + gchunk;
            __builtin_amdgcn_global_load_lds(
                (const __attribute__((address_space(1))) void*)ga,
                (__attribute__((address_space(3))) void*)(As + s * 512), 16, 0, 0);
        }
        // B_c: 8 slices, this wave's own control point
#pragma unroll
        for (int j = 0; j < 8; ++j) {
            const uint16_t* gb = Bg + (size_t)(j * 8 + srow) * 1024 + k0 + gchunk;
            __builtin_amdgcn_global_load_lds(
                (const __attribute__((address_space(1))) void*)gb,
                (__attribute__((address_space(3))) void*)(Bs + wid * 4096 + j * 512), 16, 0, 0);
        }
    };

    STAGE(0, 0);
    int cur = 0;

    for (int kt = 0; kt < 16; ++kt) {
        __syncthreads();               // STAGE(cur) landed; prev buf's reads done
        if (kt < 15) STAGE(cur ^ 1, kt + 1);   // prefetch next tile NOW

        const uint16_t* As = lds + cur * BUFSZ;
        const uint16_t* Bs = As + 4096;

#pragma unroll
        for (int ks = 0; ks < 2; ++ks) {
            const int ch = (ks * 4 + quad) ^ l7;       // physical chunk
            bf16x8 af[4], bfr[4];
#pragma unroll
            for (int mi = 0; mi < 4; ++mi) {
                const int row = mi * 16 + (lane & 15);
                af[mi] = *(const bf16x8*)(As + row * 64 + ch * 8);
            }
#pragma unroll
            for (int ni = 0; ni < 4; ++ni) {
                const int row = ni * 16 + (lane & 15);
                bfr[ni] = *(const bf16x8*)(Bs + wid * 4096 + row * 64 + ch * 8);
            }
#pragma unroll
            for (int mi = 0; mi < 4; ++mi)
#pragma unroll
                for (int ni = 0; ni < 4; ++ni)
                    acc[mi][ni] = __builtin_amdgcn_mfma_f32_16x16x32_bf16(
                        af[mi], bfr[ni], acc[mi][ni], 0, 0, 0);
        }
        cur ^= 1;
    }

    // ---- epilogue: in-block c-reduction (round-6 verified) ----
    // 1) scale by alpha[m, c=wid], publish bf16 partials to Ps.
    //    C/D layout: col = lane&15, row(64-tile) = mi*16 + quad*4 + r.
    float av[4][4];
#pragma unroll
    for (int mi = 0; mi < 4; ++mi)
#pragma unroll
        for (int r = 0; r < 4; ++r)
            av[mi][r] = alphaWS[(size_t)(tileM + mi * 16 + quad * 4 + r) * 4 + wid];

    __syncthreads();                  // all buffer-0-region reads complete
#pragma unroll
    for (int mi = 0; mi < 4; ++mi) {
#pragma unroll
        for (int r = 0; r < 4; ++r) {
            const int row = mi * 16 + quad * 4 + r;
#pragma unroll
            for (int ni = 0; ni < 4; ++ni)
                Ps[wid * (64 * PS) + row * PS + ni * 16 + (lane & 15)] =
                    f2bf(av[mi][r] * acc[mi][ni][r]);
        }
    }
    __syncthreads();

    // 2) combine: thread t -> row rr = t>>2, 16-col group cg = t&3.
    //    out[m,n] = sum_c Ps_c[m,n] + sum_c alpha[m,c]*bias[c,n]
    {
        const int rr = tid >> 2;
        const int cg = tid & 3;
        const int colb = cg * 16;
        const float4 al = *(const float4*)(alphaWS + (size_t)(tileM + rr) * 4);
        const float a[4] = {al.x, al.y, al.z, al.w};

        float res[16];
#pragma unroll
        for (int j = 0; j < 16; ++j) res[j] = 0.f;

#pragma unroll
        for (int cc = 0; cc < 4; ++cc) {
            // alpha-weighted bias (bias is L2-hot, 16KB total)
#pragma unroll
            for (int jj = 0; jj < 4; ++jj) {
                float4 bv = *(const float4*)(biases + (size_t)cc * OUT_DIM + tileN + colb + jj * 4);
                res[jj * 4 + 0] += a[cc] * bv.x;
                res[jj * 4 + 1] += a[cc] * bv.y;
                res[jj * 4 + 2] += a[cc] * bv.z;
                res[jj * 4 + 3] += a[cc] * bv.w;
            }
            // partial (ushort2 = 4B aligned: offsets all even)
            const uint16_t* p = Ps + cc * (64 * PS) + rr * PS + colb;
#pragma unroll
            for (int jj = 0; jj < 8; ++jj) {
                uint32_t pv = *(const uint32_t*)(p + jj * 2);
                res[jj * 2 + 0] += bf2f((uint16_t)(pv & 0xFFFFu));
                res[jj * 2 + 1] += bf2f((uint16_t)(pv >> 16));
            }
        }

        float* orow = out + (size_t)(tileM + rr) * OUT_DIM + tileN + colb;
#pragma unroll
        for (int jj = 0; jj < 4; ++jj) {
            float4 o = {res[jj * 4 + 0], res[jj * 4 + 1], res[jj * 4 + 2], res[jj * 4 + 3]};
            *(float4*)(orow + jj * 4) = o;
        }
    }
}

extern "C" void kernel_launch(void* const* d_in, const int* in_sizes, int n_in,
                              void* d_out, int out_size, void* d_ws, size_t ws_size,
                              hipStream_t stream)
{
    const float* x       = (const float*)d_in[0];  // (B, IN)
    const float* phase   = (const float*)d_in[1];  // (B,)
    const float* weights = (const float*)d_in[2];  // (4, OUT, IN)
    const float* biases  = (const float*)d_in[3];  // (4, OUT)
    const float* basis   = (const float*)d_in[4];  // (4, 4)
    float* out = (float*)d_out;                    // (B, OUT)

    // Workspace: xb bf16 8 MB | Wb bf16 8 MB | alpha 64 KB
    uint16_t* xb = (uint16_t*)d_ws;
    uint16_t* Wb = xb + (size_t)BATCH * IN_DIM;
    float* alphaWS = (float*)(Wb + (size_t)4 * OUT_DIM * IN_DIM);

    prep<<<2 * BATCH, 256, 0, stream>>>(x, phase, basis, weights, xb, Wb, alphaWS);

    dim3 grid(BATCH / 64, OUT_DIM / 64);   // 1024 blocks, M-fastest for L2
    gemm_fused<<<grid, 256, 0, stream>>>(xb, Wb, alphaWS, biases, out);
}